// Round 3
// baseline (242.392 us; speedup 1.0000x reference)
//
#include <hip/hip_runtime.h>

typedef __attribute__((ext_vector_type(8))) short short8;
typedef __attribute__((ext_vector_type(4))) float f32x4;
typedef __attribute__((ext_vector_type(16))) float f32x16;
typedef __attribute__((ext_vector_type(4))) int i32x4;

__device__ __forceinline__ unsigned short f2bf(float f){
  union { float f; unsigned int u; } cv; cv.f = f;
  unsigned int u = cv.u;
  u = (u + 0x7fffu + ((u >> 16) & 1u)) >> 16;
  return (unsigned short)u;
}

typedef unsigned int u32g __attribute__((address_space(1)));
typedef unsigned int u32l __attribute__((address_space(3)));
__device__ __forceinline__ void gload16(const void* g, void* l){
  __builtin_amdgcn_global_load_lds((const u32g*)g, (u32l*)l, 16, 0, 0);
}

__device__ __forceinline__ unsigned int cvtpk_bf16(float lo, float hi){
  unsigned int r;
  asm("v_cvt_pk_bf16_f32 %0, %1, %2" : "=v"(r) : "v"(lo), "v"(hi));
  return r;
}

// ---------------- reduction: per-batch mean / rstd ----------------
__global__ __launch_bounds__(256) void reduce_partial_k(const float* __restrict__ x,
                                                        float2* __restrict__ partial){
  const int b = blockIdx.y, blk = blockIdx.x;
  const float4* xp = (const float4*)(x + (size_t)b*1048576 + (size_t)blk*16384);
  float s = 0.f, sq = 0.f;
  #pragma unroll
  for (int i = 0; i < 16; ++i){
    float4 v = xp[threadIdx.x + i*256];
    s  += v.x + v.y + v.z + v.w;
    sq += v.x*v.x + v.y*v.y + v.z*v.z + v.w*v.w;
  }
  #pragma unroll
  for (int m = 1; m < 64; m <<= 1){ s += __shfl_xor(s, m); sq += __shfl_xor(sq, m); }
  __shared__ float2 acc[4];
  if ((threadIdx.x & 63) == 0) acc[threadIdx.x >> 6] = make_float2(s, sq);
  __syncthreads();
  if (threadIdx.x == 0){
    float S = 0.f, Q = 0.f;
    for (int i = 0; i < 4; ++i){ S += acc[i].x; Q += acc[i].y; }
    partial[b*64 + blk] = make_float2(S, Q);
  }
}

__global__ __launch_bounds__(256) void reduce_final_k(const float2* __restrict__ partial,
                                                      float2* __restrict__ stats){
  const int w = threadIdx.x >> 6, lane = threadIdx.x & 63;
  float2 p = partial[w*64 + lane];
  float s = p.x, q = p.y;
  #pragma unroll
  for (int m = 1; m < 64; m <<= 1){ s += __shfl_xor(s, m); q += __shfl_xor(q, m); }
  if (lane == 0){
    const float inv = 1.0f/1048576.0f;
    float mean = s*inv;
    float var  = q*inv - mean*mean;
    stats[w] = make_float2(mean, rsqrtf(var + 1e-6f));
  }
}

// ---------------- weight conversion (fold scale*log2e into Q) ----------------
__global__ __launch_bounds__(256) void convert_w_k(const float* __restrict__ qkv_w,
                                                   const float* __restrict__ qkv_b,
                                                   const float* __restrict__ proj_w,
                                                   unsigned short* __restrict__ Wqk,
                                                   unsigned short* __restrict__ Wv,
                                                   unsigned short* __restrict__ Wp,
                                                   float* __restrict__ bias_qk){
  const float SQ = 0.0625f * 1.44269504088896340736f; // (C^-0.5) * log2(e)
  int id = blockIdx.x * 256 + threadIdx.x;
  if (id < 131072){                       // q,k rows (o < 512)
    int o = id >> 8;
    float sc = (o < 256) ? SQ : 1.0f;
    Wqk[id] = f2bf(qkv_w[id] * sc);
    if (id < 512) bias_qk[id] = qkv_b[id] * ((id < 256) ? SQ : 1.0f);
  } else if (id < 196608){                // v rows (o in [512,768))
    Wv[id - 131072] = f2bf(qkv_w[id]);
  } else {                                // proj
    int j = id - 196608;
    Wp[j] = f2bf(proj_w[j]);
  }
}

// ---------------- GroupNorm + transpose: x[b][c][n] -> xn_t[b][n][c] bf16 ----------------
__global__ __launch_bounds__(256) void norm_transpose_k(const float* __restrict__ x,
                                                        const float* __restrict__ gamma,
                                                        const float* __restrict__ beta,
                                                        const float2* __restrict__ stats,
                                                        unsigned short* __restrict__ xnt){
  __shared__ float tile[64][65];
  const int b = blockIdx.z, n0 = blockIdx.x*64, c0 = blockIdx.y*64;
  const float2 st = stats[b];
  const int t = threadIdx.x;
  const int col = t & 63, rb = t >> 6;
  #pragma unroll
  for (int i = 0; i < 16; ++i){
    int rr = i*4 + rb;
    float xv = x[((size_t)b*256 + c0 + rr)*4096 + n0 + col];
    tile[rr][col] = (xv - st.x) * st.y * gamma[c0+rr] + beta[c0+rr];
  }
  __syncthreads();
  #pragma unroll
  for (int i = 0; i < 16; ++i){
    int nr = i*4 + rb;
    xnt[((size_t)b*4096 + n0 + nr)*256 + c0 + col] = f2bf(tile[col][nr]);
  }
}

// ---------------- NT GEMM: C[m][n] = sum_k A[m][k]*B[n][k], K=256 ----------------
__global__ __launch_bounds__(256) void gemm_nt_k(const unsigned short* __restrict__ A,
                                                 const unsigned short* __restrict__ B,
                                                 int lda, int ldb, long sA, long sB,
                                                 const float* __restrict__ bias_m,
                                                 const float* __restrict__ bias_n,
                                                 const float* __restrict__ resid, long sR,
                                                 float* __restrict__ outF,
                                                 unsigned short* __restrict__ outB,
                                                 int ldc, long sC){
  __shared__ unsigned short As[64][40];
  __shared__ unsigned short Bs[64][40];
  const int b  = blockIdx.z;
  const int m0 = blockIdx.x * 64, n0 = blockIdx.y * 64;
  const unsigned short* Ab = A + (size_t)b * sA;
  const unsigned short* Bb = B + (size_t)b * sB;
  const int t = threadIdx.x;
  const int lane = t & 63, w = t >> 6;
  const int g = lane >> 4, r = lane & 15;
  const int wm = (w >> 1) * 32, wn = (w & 1) * 32;
  const int lrow = t >> 2, lcol = (t & 3) * 8;
  f32x4 acc00 = {0,0,0,0}, acc01 = {0,0,0,0}, acc10 = {0,0,0,0}, acc11 = {0,0,0,0};
  for (int ks = 0; ks < 8; ++ks){
    short8 av = *(const short8*)(Ab + (size_t)(m0 + lrow) * lda + ks*32 + lcol);
    short8 bv = *(const short8*)(Bb + (size_t)(n0 + lrow) * ldb + ks*32 + lcol);
    __syncthreads();
    *(short8*)&As[lrow][lcol] = av;
    *(short8*)&Bs[lrow][lcol] = bv;
    __syncthreads();
    short8 af0 = *(const short8*)&As[wm + r][g*8];
    short8 af1 = *(const short8*)&As[wm + 16 + r][g*8];
    short8 bf0 = *(const short8*)&Bs[wn + r][g*8];
    short8 bf1 = *(const short8*)&Bs[wn + 16 + r][g*8];
    acc00 = __builtin_amdgcn_mfma_f32_16x16x32_bf16(af0, bf0, acc00, 0, 0, 0);
    acc01 = __builtin_amdgcn_mfma_f32_16x16x32_bf16(af0, bf1, acc01, 0, 0, 0);
    acc10 = __builtin_amdgcn_mfma_f32_16x16x32_bf16(af1, bf0, acc10, 0, 0, 0);
    acc11 = __builtin_amdgcn_mfma_f32_16x16x32_bf16(af1, bf1, acc11, 0, 0, 0);
  }
  f32x4 accs[2][2] = {{acc00, acc01},{acc10, acc11}};
  #pragma unroll
  for (int mi = 0; mi < 2; ++mi)
    #pragma unroll
    for (int ni = 0; ni < 2; ++ni)
      #pragma unroll
      for (int j = 0; j < 4; ++j){
        int gm = m0 + wm + mi*16 + g*4 + j;
        int gn = n0 + wn + ni*16 + r;
        float vv = accs[mi][ni][j];
        if (bias_m) vv += bias_m[gm];
        if (bias_n) vv += bias_n[gn];
        if (resid)  vv += resid[(size_t)b*sR + (size_t)gm*ldc + gn];
        size_t off = (size_t)b*sC + (size_t)gm*ldc + gn;
        if (outB) outB[off] = f2bf(vv); else outF[off] = vv;
      }
}

// ---------------- flash attention: 8 waves = 4 k-groups x 2 q-waves, 32x32x16 MFMA ----------------
// q,k in qk[b][n][512] (q=c<256, k=c>=256), v in vbuf[b][c][n]. Output ho[b][n][c] bf16.
// Swapped QK^T (S^T = K*Q): softmax lane-local; P stays in registers via cvt_pk + permlane32_swap.
__global__ __launch_bounds__(512, 2) void attn_k(const unsigned short* __restrict__ qk,
                                                 const unsigned short* __restrict__ vbuf,
                                                 unsigned short* __restrict__ ho){
  __shared__ char smem[131072];   // 4 groups x (K 16KB + V 16KB); merge overlays
  const int b = blockIdx.y, q0 = blockIdx.x * 64;
  const int t = threadIdx.x, lane = t & 63, w = t >> 6;
  const int g = w >> 1, qw = w & 1;
  const int hi = lane >> 5, l31 = lane & 31;
  char* Kg = smem + g*32768;          // [32 rows][512B] (XOR-swizzled contents)
  char* Vg = Kg + 16384;              // [256 rows][64B] (XOR-swizzled contents)
  const unsigned short* qkb = qk + (size_t)b * 4096 * 512;
  const unsigned short* vb  = vbuf + (size_t)b * 256 * 4096;

  // Q fragments: wave owns q-rows q0 + qw*32 + l31; B-operand layout [q=l&31][k=(l>>5)*8+j]
  short8 qf[16];
  {
    const unsigned short* qrow = qkb + (size_t)(q0 + qw*32 + l31) * 512;
    #pragma unroll
    for (int s = 0; s < 16; ++s) qf[s] = *(const short8*)(qrow + s*16 + hi*8);
  }
  f32x16 O[8];
  #pragma unroll
  for (int cb = 0; cb < 8; ++cb)
    #pragma unroll
    for (int j = 0; j < 16; ++j) O[cb][j] = 0.f;
  float mref = -1e30f, lrun = 0.f;

  const int kswz = (l31 & 15) << 4;               // K read swizzle (row = l31)
  const int vswz = ((l31 >> 1) & 3) << 4;         // V read swizzle ((c>>1)&3 depends only on l31)

  for (int kt = 0; kt < 32; ++kt){
    const int kc = g*1024 + kt*32;
    __syncthreads();                               // prior tile fully consumed
    // ---- stage K tile (this wave stages its qw-half: 16 rows, 8 calls) ----
    #pragma unroll
    for (int ii = 0; ii < 8; ++ii){
      int row = qw*16 + 2*ii + hi;
      const unsigned short* src = qkb + (size_t)(kc + row)*512 + 256
                                + ((((l31*16) ^ ((row & 15) << 4))) >> 1);
      gload16(src, Kg + (qw*16 + 2*ii)*512);
    }
    __syncthreads();                               // K staged (drains vmcnt)
    // ---- issue V stage (latency hides under QK^T) ----
    #pragma unroll
    for (int ii = 0; ii < 8; ++ii){
      int c = qw*128 + 16*ii + (lane >> 2);
      const unsigned short* src = vb + (size_t)c*4096 + kc
                                + (((((lane & 3)*16) ^ (((c >> 1) & 3) << 4))) >> 1);
      gload16(src, Vg + (qw*128 + 16*ii)*64);
    }
    // ---- S^T = K Q : one 32x32 block, 16 k-steps ----
    f32x16 S;
    #pragma unroll
    for (int j = 0; j < 16; ++j) S[j] = 0.f;
    #pragma unroll
    for (int s = 0; s < 16; ++s){
      short8 kf = *(const short8*)(Kg + l31*512 + ((s*32 + hi*16) ^ kswz));
      S = __builtin_amdgcn_mfma_f32_32x32x16_bf16(kf, qf[s], S, 0, 0, 0);
    }
    // ---- online softmax over k (lane-local: 16 regs + cross-half) ----
    float m01 = fmaxf(S[0], S[1]),   m23 = fmaxf(S[2], S[3]);
    float m45 = fmaxf(S[4], S[5]),   m67 = fmaxf(S[6], S[7]);
    float m89 = fmaxf(S[8], S[9]),   mab = fmaxf(S[10], S[11]);
    float mcd = fmaxf(S[12], S[13]), mef = fmaxf(S[14], S[15]);
    float mx = fmaxf(fmaxf(fmaxf(m01, m23), fmaxf(m45, m67)),
                     fmaxf(fmaxf(m89, mab), fmaxf(mcd, mef)));
    mx = fmaxf(mx, __shfl_xor(mx, 32));
    if (__any(mx > mref + 8.0f)){
      float mnew = fmaxf(mref, mx);
      float al = exp2f(mref - mnew);
      lrun *= al;
      #pragma unroll
      for (int cb = 0; cb < 8; ++cb)
        #pragma unroll
        for (int j = 0; j < 16; ++j) O[cb][j] *= al;
      mref = mnew;
    }
    float p[16];
    #pragma unroll
    for (int j = 0; j < 16; ++j) p[j] = exp2f(S[j] - mref);
    float ps = ((p[0]+p[1]) + (p[2]+p[3])) + ((p[4]+p[5]) + (p[6]+p[7]))
             + ((p[8]+p[9]) + (p[10]+p[11])) + ((p[12]+p[13]) + (p[14]+p[15]));
    lrun += ps;                                    // lane-partial; combined at end
    // ---- pack P -> bf16 B-fragments (cvt_pk + permlane32_swap, no LDS) ----
    unsigned int w0 = cvtpk_bf16(p[0],  p[1]),  w1 = cvtpk_bf16(p[2],  p[3]);
    unsigned int w2 = cvtpk_bf16(p[4],  p[5]),  w3 = cvtpk_bf16(p[6],  p[7]);
    unsigned int w4 = cvtpk_bf16(p[8],  p[9]),  w5 = cvtpk_bf16(p[10], p[11]);
    unsigned int w6 = cvtpk_bf16(p[12], p[13]), w7 = cvtpk_bf16(p[14], p[15]);
    asm("v_permlane32_swap_b32 %0, %1" : "+v"(w0), "+v"(w2));
    asm("v_permlane32_swap_b32 %0, %1" : "+v"(w1), "+v"(w3));
    asm("v_permlane32_swap_b32 %0, %1" : "+v"(w4), "+v"(w6));
    asm("v_permlane32_swap_b32 %0, %1" : "+v"(w5), "+v"(w7));
    i32x4 pw0 = {(int)w0, (int)w1, (int)w2, (int)w3};
    i32x4 pw1 = {(int)w4, (int)w5, (int)w6, (int)w7};
    short8 pa0 = __builtin_bit_cast(short8, pw0);
    short8 pa1 = __builtin_bit_cast(short8, pw1);
    __syncthreads();                               // V staged (drains vmcnt)
    // ---- O^T += V P^T : 8 c-blocks x 2 k-steps ----
    #pragma unroll
    for (int cb = 0; cb < 8; ++cb){
      const char* vrow = Vg + (cb*32 + l31)*64;
      short8 vf0 = *(const short8*)(vrow + ((hi*16) ^ vswz));
      O[cb] = __builtin_amdgcn_mfma_f32_32x32x16_bf16(vf0, pa0, O[cb], 0, 0, 0);
      short8 vf1 = *(const short8*)(vrow + ((32 + hi*16) ^ vswz));
      O[cb] = __builtin_amdgcn_mfma_f32_32x32x16_bf16(vf1, pa1, O[cb], 0, 0, 0);
    }
  }

  // ---- merge 4 k-chunks (3 rounds through LDS overlay) ----
  float lf = lrun + __shfl_xor(lrun, 32);
  float*  Of  = (float*)smem;                      // [64][260] f32
  float2* mlb = (float2*)(smem + 66560);           // [64]
  __syncthreads();
  for (int r = 1; r < 4; ++r){
    if (g == r){
      #pragma unroll
      for (int cb = 0; cb < 8; ++cb)
        #pragma unroll
        for (int j = 0; j < 16; ++j){
          int c = cb*32 + (j & 3) + 8*(j >> 2) + 4*hi;
          Of[(qw*32 + l31)*260 + c] = O[cb][j];
        }
      if (lane < 32) mlb[qw*32 + lane] = make_float2(mref, lf);
    }
    __syncthreads();
    if (g == 0){
      float2 ml = mlb[qw*32 + l31];
      float M  = fmaxf(mref, ml.x);
      float e0 = exp2f(mref - M), e1 = exp2f(ml.x - M);
      #pragma unroll
      for (int cb = 0; cb < 8; ++cb)
        #pragma unroll
        for (int j = 0; j < 16; ++j){
          int c = cb*32 + (j & 3) + 8*(j >> 2) + 4*hi;
          O[cb][j] = O[cb][j]*e0 + Of[(qw*32 + l31)*260 + c]*e1;
        }
      lf = lf*e0 + ml.y*e1;
      mref = M;
    }
    __syncthreads();
  }
  if (g == 0){
    float inv = 1.0f / lf;
    #pragma unroll
    for (int cb = 0; cb < 8; ++cb)
      #pragma unroll
      for (int j = 0; j < 16; ++j){
        int c = cb*32 + (j & 3) + 8*(j >> 2) + 4*hi;
        Of[(qw*32 + l31)*260 + c] = O[cb][j] * inv;
      }
  }
  __syncthreads();
  // ---- coalesced bf16 write-out: thread t -> (q = t>>3, c0 = (t&7)*32) ----
  {
    int q = t >> 3, c0 = (t & 7) * 32;
    const float* rowp = Of + q*260 + c0;
    unsigned short* dst = ho + ((size_t)(b*4096 + q0 + q))*256 + c0;
    #pragma unroll
    for (int i = 0; i < 8; ++i){
      float4 v = *(const float4*)(rowp + i*4);
      ushort4 u;
      u.x = f2bf(v.x); u.y = f2bf(v.y); u.z = f2bf(v.z); u.w = f2bf(v.w);
      *(ushort4*)(dst + i*4) = u;
    }
  }
}

// ---------------- launch ----------------
extern "C" void kernel_launch(void* const* d_in, const int* in_sizes, int n_in,
                              void* d_out, int out_size, void* d_ws, size_t ws_size,
                              hipStream_t stream){
  const float* x      = (const float*)d_in[0];
  const float* gamma  = (const float*)d_in[1];
  const float* beta   = (const float*)d_in[2];
  const float* qkv_w  = (const float*)d_in[3];
  const float* qkv_b  = (const float*)d_in[4];
  const float* proj_w = (const float*)d_in[5];
  const float* proj_b = (const float*)d_in[6];
  float* out = (float*)d_out;
  char* ws = (char*)d_ws;

  float2* partial        = (float2*)(ws + 0);        // 2048 B
  float2* stats          = (float2*)(ws + 2048);     // 32 B
  float*  bias_qk        = (float*)(ws + 4096);      // 2048 B
  unsigned short* Wqk    = (unsigned short*)(ws + 8192);      // 512x256 bf16
  unsigned short* Wv     = (unsigned short*)(ws + 270336);    // 256x256
  unsigned short* Wp     = (unsigned short*)(ws + 401408);    // 256x256
  unsigned short* xnt    = (unsigned short*)(ws + 532480);    // 4x4096x256 bf16 (8.4 MB)
  unsigned short* qkbuf  = (unsigned short*)(ws + 8921088);   // 4x4096x512 bf16 (16.8 MB)
  unsigned short* vbuf   = (unsigned short*)(ws + 25698304);  // 4x256x4096 bf16 (8.4 MB)
  unsigned short* ho     = xnt;  // xnt dead after QKV gemms -> reuse for attention output

  reduce_partial_k<<<dim3(64,4), 256, 0, stream>>>(x, partial);
  reduce_final_k<<<1, 256, 0, stream>>>(partial, stats);
  convert_w_k<<<1024, 256, 0, stream>>>(qkv_w, qkv_b, proj_w, Wqk, Wv, Wp, bias_qk);
  norm_transpose_k<<<dim3(64,4,4), 256, 0, stream>>>(x, gamma, beta, stats, xnt);
  // qk[b][n][o] = xn_t[b][n][:] . Wqk[o][:]   (M=4096, N=512)
  gemm_nt_k<<<dim3(64,8,4), 256, 0, stream>>>(xnt, Wqk, 256, 256, 4096L*256, 0,
      nullptr, bias_qk, nullptr, 0, nullptr, qkbuf, 512, 4096L*512);
  // v[b][o][n] = Wv[o][:] . xn_t[b][n][:]     (M=256, N=4096)
  gemm_nt_k<<<dim3(4,64,4), 256, 0, stream>>>(Wv, xnt, 256, 256, 0, 4096L*256,
      qkv_b + 512, nullptr, nullptr, 0, nullptr, vbuf, 4096, 256L*4096);
  attn_k<<<dim3(64,4), 512, 0, stream>>>(qkbuf, vbuf, ho);
  // out[b][o][n] = Wp[o][:] . ho[b][n][:] + proj_b[o] + x[b][o][n]
  gemm_nt_k<<<dim3(4,64,4), 256, 0, stream>>>(Wp, ho, 256, 256, 0, 4096L*256,
      proj_b, nullptr, x, 1048576L, out, nullptr, 4096, 1048576L);
}

// Round 4
// 189.893 us; speedup vs baseline: 1.2765x; 1.2765x over previous
//
#include <hip/hip_runtime.h>

typedef __attribute__((ext_vector_type(8))) short short8;
typedef __attribute__((ext_vector_type(4))) float f32x4;
typedef __attribute__((ext_vector_type(16))) float f32x16;
typedef __attribute__((ext_vector_type(4))) int i32x4;

__device__ __forceinline__ unsigned short f2bf(float f){
  union { float f; unsigned int u; } cv; cv.f = f;
  unsigned int u = cv.u;
  u = (u + 0x7fffu + ((u >> 16) & 1u)) >> 16;
  return (unsigned short)u;
}

typedef unsigned int u32g __attribute__((address_space(1)));
typedef unsigned int u32l __attribute__((address_space(3)));
__device__ __forceinline__ void gload16(const void* g, void* l){
  __builtin_amdgcn_global_load_lds((const u32g*)g, (u32l*)l, 16, 0, 0);
}

__device__ __forceinline__ unsigned int cvtpk_bf16(float lo, float hi){
  unsigned int r;
  asm("v_cvt_pk_bf16_f32 %0, %1, %2" : "=v"(r) : "v"(lo), "v"(hi));
  return r;
}

#define BARRIER() asm volatile("s_barrier" ::: "memory")
#define WAITV16() asm volatile("s_waitcnt vmcnt(16)" ::: "memory")

// ---------------- reduction: per-batch mean / rstd ----------------
__global__ __launch_bounds__(256) void reduce_partial_k(const float* __restrict__ x,
                                                        float2* __restrict__ partial){
  const int b = blockIdx.y, blk = blockIdx.x;
  const float4* xp = (const float4*)(x + (size_t)b*1048576 + (size_t)blk*16384);
  float s = 0.f, sq = 0.f;
  #pragma unroll
  for (int i = 0; i < 16; ++i){
    float4 v = xp[threadIdx.x + i*256];
    s  += v.x + v.y + v.z + v.w;
    sq += v.x*v.x + v.y*v.y + v.z*v.z + v.w*v.w;
  }
  #pragma unroll
  for (int m = 1; m < 64; m <<= 1){ s += __shfl_xor(s, m); sq += __shfl_xor(sq, m); }
  __shared__ float2 acc[4];
  if ((threadIdx.x & 63) == 0) acc[threadIdx.x >> 6] = make_float2(s, sq);
  __syncthreads();
  if (threadIdx.x == 0){
    float S = 0.f, Q = 0.f;
    for (int i = 0; i < 4; ++i){ S += acc[i].x; Q += acc[i].y; }
    partial[b*64 + blk] = make_float2(S, Q);
  }
}

__global__ __launch_bounds__(256) void reduce_final_k(const float2* __restrict__ partial,
                                                      float2* __restrict__ stats){
  const int w = threadIdx.x >> 6, lane = threadIdx.x & 63;
  float2 p = partial[w*64 + lane];
  float s = p.x, q = p.y;
  #pragma unroll
  for (int m = 1; m < 64; m <<= 1){ s += __shfl_xor(s, m); q += __shfl_xor(q, m); }
  if (lane == 0){
    const float inv = 1.0f/1048576.0f;
    float mean = s*inv;
    float var  = q*inv - mean*mean;
    stats[w] = make_float2(mean, rsqrtf(var + 1e-6f));
  }
}

// ---------------- weight conversion (fold scale*log2e into Q) ----------------
__global__ __launch_bounds__(256) void convert_w_k(const float* __restrict__ qkv_w,
                                                   const float* __restrict__ qkv_b,
                                                   const float* __restrict__ proj_w,
                                                   unsigned short* __restrict__ Wqk,
                                                   unsigned short* __restrict__ Wv,
                                                   unsigned short* __restrict__ Wp,
                                                   float* __restrict__ bias_qk){
  const float SQ = 0.0625f * 1.44269504088896340736f; // (C^-0.5) * log2(e)
  int id = blockIdx.x * 256 + threadIdx.x;
  if (id < 131072){                       // q,k rows (o < 512)
    int o = id >> 8;
    float sc = (o < 256) ? SQ : 1.0f;
    Wqk[id] = f2bf(qkv_w[id] * sc);
    if (id < 512) bias_qk[id] = qkv_b[id] * ((id < 256) ? SQ : 1.0f);
  } else if (id < 196608){                // v rows (o in [512,768))
    Wv[id - 131072] = f2bf(qkv_w[id]);
  } else {                                // proj
    int j = id - 196608;
    Wp[j] = f2bf(proj_w[j]);
  }
}

// ---------------- GroupNorm + transpose: x[b][c][n] -> xn_t[b][n][c] bf16 ----------------
__global__ __launch_bounds__(256) void norm_transpose_k(const float* __restrict__ x,
                                                        const float* __restrict__ gamma,
                                                        const float* __restrict__ beta,
                                                        const float2* __restrict__ stats,
                                                        unsigned short* __restrict__ xnt){
  __shared__ float tile[64][65];
  const int b = blockIdx.z, n0 = blockIdx.x*64, c0 = blockIdx.y*64;
  const float2 st = stats[b];
  const int t = threadIdx.x;
  const int col = t & 63, rb = t >> 6;
  #pragma unroll
  for (int i = 0; i < 16; ++i){
    int rr = i*4 + rb;
    float xv = x[((size_t)b*256 + c0 + rr)*4096 + n0 + col];
    tile[rr][col] = (xv - st.x) * st.y * gamma[c0+rr] + beta[c0+rr];
  }
  __syncthreads();
  #pragma unroll
  for (int i = 0; i < 16; ++i){
    int nr = i*4 + rb;
    xnt[((size_t)b*4096 + n0 + nr)*256 + c0 + col] = f2bf(tile[col][nr]);
  }
}

// ---------------- NT GEMM: C[m][n] = sum_k A[m][k]*B[n][k], K=256 ----------------
__global__ __launch_bounds__(256) void gemm_nt_k(const unsigned short* __restrict__ A,
                                                 const unsigned short* __restrict__ B,
                                                 int lda, int ldb, long sA, long sB,
                                                 const float* __restrict__ bias_m,
                                                 const float* __restrict__ bias_n,
                                                 const float* __restrict__ resid, long sR,
                                                 float* __restrict__ outF,
                                                 unsigned short* __restrict__ outB,
                                                 int ldc, long sC){
  __shared__ unsigned short As[64][40];
  __shared__ unsigned short Bs[64][40];
  const int b  = blockIdx.z;
  const int m0 = blockIdx.x * 64, n0 = blockIdx.y * 64;
  const unsigned short* Ab = A + (size_t)b * sA;
  const unsigned short* Bb = B + (size_t)b * sB;
  const int t = threadIdx.x;
  const int lane = t & 63, w = t >> 6;
  const int g = lane >> 4, r = lane & 15;
  const int wm = (w >> 1) * 32, wn = (w & 1) * 32;
  const int lrow = t >> 2, lcol = (t & 3) * 8;
  f32x4 acc00 = {0,0,0,0}, acc01 = {0,0,0,0}, acc10 = {0,0,0,0}, acc11 = {0,0,0,0};
  for (int ks = 0; ks < 8; ++ks){
    short8 av = *(const short8*)(Ab + (size_t)(m0 + lrow) * lda + ks*32 + lcol);
    short8 bv = *(const short8*)(Bb + (size_t)(n0 + lrow) * ldb + ks*32 + lcol);
    __syncthreads();
    *(short8*)&As[lrow][lcol] = av;
    *(short8*)&Bs[lrow][lcol] = bv;
    __syncthreads();
    short8 af0 = *(const short8*)&As[wm + r][g*8];
    short8 af1 = *(const short8*)&As[wm + 16 + r][g*8];
    short8 bf0 = *(const short8*)&Bs[wn + r][g*8];
    short8 bf1 = *(const short8*)&Bs[wn + 16 + r][g*8];
    acc00 = __builtin_amdgcn_mfma_f32_16x16x32_bf16(af0, bf0, acc00, 0, 0, 0);
    acc01 = __builtin_amdgcn_mfma_f32_16x16x32_bf16(af0, bf1, acc01, 0, 0, 0);
    acc10 = __builtin_amdgcn_mfma_f32_16x16x32_bf16(af1, bf0, acc10, 0, 0, 0);
    acc11 = __builtin_amdgcn_mfma_f32_16x16x32_bf16(af1, bf1, acc11, 0, 0, 0);
  }
  f32x4 accs[2][2] = {{acc00, acc01},{acc10, acc11}};
  #pragma unroll
  for (int mi = 0; mi < 2; ++mi)
    #pragma unroll
    for (int ni = 0; ni < 2; ++ni)
      #pragma unroll
      for (int j = 0; j < 4; ++j){
        int gm = m0 + wm + mi*16 + g*4 + j;
        int gn = n0 + wn + ni*16 + r;
        float vv = accs[mi][ni][j];
        if (bias_m) vv += bias_m[gm];
        if (bias_n) vv += bias_n[gn];
        if (resid)  vv += resid[(size_t)b*sR + (size_t)gm*ldc + gn];
        size_t off = (size_t)b*sC + (size_t)gm*ldc + gn;
        if (outB) outB[off] = f2bf(vv); else outF[off] = vv;
      }
}

// ---------------- flash attention: 4 waves = 2 k-groups x 2 q-waves, full async dbuf ----------------
// q,k in qk[b][n][512] (q=c<256, k=c>=256), v in vbuf[b][c][n]. Output ho[b][n][c] bf16.
// Double-buffered LDS, counted vmcnt (loads for tile t+1 stay in flight across barriers).
__global__ __launch_bounds__(256, 1) void attn_k(const unsigned short* __restrict__ qk,
                                                 const unsigned short* __restrict__ vbuf,
                                                 unsigned short* __restrict__ ho){
  __shared__ __align__(16) char smem[131072];  // [buf2][group2][K 16KB | V 16KB]
  const int b = blockIdx.y, q0 = blockIdx.x * 64;
  const int t = threadIdx.x, lane = t & 63, w = t >> 6;
  const int g = w >> 1;            // k-group: 0 -> k in [0,2048), 1 -> [2048,4096)
  const int qw = w & 1;            // q-wave (32 rows) and staging role (0=K, 1=V)
  const int hi = lane >> 5, l31 = lane & 31;
  const unsigned short* qkb = qk + (size_t)b * 4096 * 512;
  const unsigned short* vb  = vbuf + (size_t)b * 256 * 4096;

  // ---- staging helpers (wave-uniform LDS dest, pre-swizzled global source) ----
  auto stageK = [&](int kc, char* Kdst){       // 32 rows x 512B
    #pragma unroll
    for (int ii = 0; ii < 16; ++ii){
      int row = 2*ii + hi;
      const unsigned short* src = qkb + (size_t)(kc + row)*512 + 256
                                + (((l31*16) ^ ((row & 15) << 4)) >> 1);
      gload16(src, Kdst + ii*1024);
    }
  };
  auto stageV = [&](int kc, char* Vdst){       // 256 rows x 64B
    #pragma unroll
    for (int ii = 0; ii < 16; ++ii){
      int c = 16*ii + (lane >> 2);
      const unsigned short* src = vb + (size_t)c*4096 + kc
                                + ((((lane & 3)*16) ^ (((lane >> 3) & 3) << 4)) >> 1);
      gload16(src, Vdst + ii*1024);
    }
  };

  // ---- Q fragments: wave owns q-rows q0 + qw*32 + l31 (B-operand) ----
  short8 qf[16];
  {
    const unsigned short* qrow = qkb + (size_t)(q0 + qw*32 + l31) * 512;
    #pragma unroll
    for (int s = 0; s < 16; ++s) qf[s] = *(const short8*)(qrow + s*16 + hi*8);
  }

  // ---- prologue: stage tiles 0 and 1 ----
  {
    char* b0 = smem + g*32768;
    char* b1 = smem + 65536 + g*32768;
    int kc0 = g*2048, kc1 = g*2048 + 32;
    if (qw == 0){ stageK(kc0, b0);        stageK(kc1, b1); }
    else        { stageV(kc0, b0 + 16384); stageV(kc1, b1 + 16384); }
  }

  f32x16 O[8];
  #pragma unroll
  for (int cb = 0; cb < 8; ++cb)
    #pragma unroll
    for (int j = 0; j < 16; ++j) O[cb][j] = 0.f;
  float mref = -1e30f, lrun = 0.f;

  const int kswz = (l31 & 15) << 4;
  const int vswz = ((l31 >> 1) & 3) << 4;

  for (int kt = 0; kt < 64; ++kt){
    char* bb = smem + (kt & 1)*65536 + g*32768;
    const char* Kt = bb;
    const char* Vt = bb + 16384;

    WAITV16();       // tile kt's 16 loads done (tile kt+1's 16 stay in flight)
    BARRIER();       // all waves' staging of tile kt visible

    // ---- S^T = K·Q : 16 c-steps, 2 accumulation chains for dep-latency ----
    f32x16 Sa, Sb;
    #pragma unroll
    for (int j = 0; j < 16; ++j){ Sa[j] = 0.f; Sb[j] = 0.f; }
    #pragma unroll
    for (int s = 0; s < 8; ++s){
      short8 k0 = *(const short8*)(Kt + l31*512 + (((2*s  )*32 + hi*16) ^ kswz));
      short8 k1 = *(const short8*)(Kt + l31*512 + (((2*s+1)*32 + hi*16) ^ kswz));
      Sa = __builtin_amdgcn_mfma_f32_32x32x16_bf16(k0, qf[2*s  ], Sa, 0, 0, 0);
      Sb = __builtin_amdgcn_mfma_f32_32x32x16_bf16(k1, qf[2*s+1], Sb, 0, 0, 0);
    }
    f32x16 S = Sa + Sb;

    // ---- online softmax over k (lane-local + cross-half), defer-max THR=8 ----
    float m01 = fmaxf(S[0], S[1]),   m23 = fmaxf(S[2], S[3]);
    float m45 = fmaxf(S[4], S[5]),   m67 = fmaxf(S[6], S[7]);
    float m89 = fmaxf(S[8], S[9]),   mab = fmaxf(S[10], S[11]);
    float mcd = fmaxf(S[12], S[13]), mef = fmaxf(S[14], S[15]);
    float mx = fmaxf(fmaxf(fmaxf(m01, m23), fmaxf(m45, m67)),
                     fmaxf(fmaxf(m89, mab), fmaxf(mcd, mef)));
    mx = fmaxf(mx, __shfl_xor(mx, 32));
    if (__any(mx > mref + 8.0f)){
      float mnew = fmaxf(mref, mx);
      float al = exp2f(mref - mnew);
      lrun *= al;
      #pragma unroll
      for (int cb = 0; cb < 8; ++cb)
        #pragma unroll
        for (int j = 0; j < 16; ++j) O[cb][j] *= al;
      mref = mnew;
    }
    float p[16];
    #pragma unroll
    for (int j = 0; j < 16; ++j) p[j] = exp2f(S[j] - mref);
    lrun += ((p[0]+p[1]) + (p[2]+p[3])) + ((p[4]+p[5]) + (p[6]+p[7]))
          + ((p[8]+p[9]) + (p[10]+p[11])) + ((p[12]+p[13]) + (p[14]+p[15]));

    // ---- pack P -> bf16 B-fragments (cvt_pk + permlane32_swap, in-register) ----
    unsigned int w0 = cvtpk_bf16(p[0],  p[1]),  w1 = cvtpk_bf16(p[2],  p[3]);
    unsigned int w2 = cvtpk_bf16(p[4],  p[5]),  w3 = cvtpk_bf16(p[6],  p[7]);
    unsigned int w4 = cvtpk_bf16(p[8],  p[9]),  w5 = cvtpk_bf16(p[10], p[11]);
    unsigned int w6 = cvtpk_bf16(p[12], p[13]), w7 = cvtpk_bf16(p[14], p[15]);
    asm("v_permlane32_swap_b32 %0, %1" : "+v"(w0), "+v"(w2));
    asm("v_permlane32_swap_b32 %0, %1" : "+v"(w1), "+v"(w3));
    asm("v_permlane32_swap_b32 %0, %1" : "+v"(w4), "+v"(w6));
    asm("v_permlane32_swap_b32 %0, %1" : "+v"(w5), "+v"(w7));
    i32x4 pw0 = {(int)w0, (int)w1, (int)w2, (int)w3};
    i32x4 pw1 = {(int)w4, (int)w5, (int)w6, (int)w7};
    short8 pa0 = __builtin_bit_cast(short8, pw0);
    short8 pa1 = __builtin_bit_cast(short8, pw1);

    // ---- O^T += V·P^T : 8 independent c-block chains ----
    #pragma unroll
    for (int cb = 0; cb < 8; ++cb){
      const char* vrow = Vt + (cb*32 + l31)*64;
      short8 vf0 = *(const short8*)(vrow + ((hi*16) ^ vswz));
      O[cb] = __builtin_amdgcn_mfma_f32_32x32x16_bf16(vf0, pa0, O[cb], 0, 0, 0);
      short8 vf1 = *(const short8*)(vrow + ((32 + hi*16) ^ vswz));
      O[cb] = __builtin_amdgcn_mfma_f32_32x32x16_bf16(vf1, pa1, O[cb], 0, 0, 0);
    }

    BARRIER();       // all waves done reading tile kt's buffer

    // ---- stage tile kt+2 into the buffer just consumed (clamped; count-uniform) ----
    int kn = kt + 2; if (kn > 63) kn = 63;
    int kc = g*2048 + kn*32;
    if (qw == 0) stageK(kc, bb);
    else         stageV(kc, bb + 16384);
  }

  // ---- merge the two k-groups (1 round through LDS overlay) ----
  float lf = lrun + __shfl_xor(lrun, 32);
  __syncthreads();                                  // full drain (trailing stages land)
  float*  Of  = (float*)smem;                       // [64][260] f32
  float2* mlb = (float2*)(smem + 66560);            // [64]
  if (g == 1){
    #pragma unroll
    for (int cb = 0; cb < 8; ++cb)
      #pragma unroll
      for (int j = 0; j < 16; ++j){
        int c = cb*32 + (j & 3) + 8*(j >> 2) + 4*hi;
        Of[(qw*32 + l31)*260 + c] = O[cb][j];
      }
    if (lane < 32) mlb[qw*32 + lane] = make_float2(mref, lf);
  }
  __syncthreads();
  if (g == 0){
    float2 ml = mlb[qw*32 + l31];
    float M  = fmaxf(mref, ml.x);
    float e0 = exp2f(mref - M), e1 = exp2f(ml.x - M);
    float inv = 1.0f / (lf*e0 + ml.y*e1);
    #pragma unroll
    for (int cb = 0; cb < 8; ++cb)
      #pragma unroll
      for (int j = 0; j < 16; ++j){
        int c = cb*32 + (j & 3) + 8*(j >> 2) + 4*hi;
        Of[(qw*32 + l31)*260 + c] = (O[cb][j]*e0 + Of[(qw*32 + l31)*260 + c]*e1) * inv;
      }
  }
  __syncthreads();
  // ---- coalesced bf16 write-out: thread t -> row q = t>>2, 8 chunks of 8 c ----
  {
    int q = t >> 2, sub = t & 3;
    const float* rowp = Of + q*260;
    unsigned short* dst = ho + ((size_t)(b*4096 + q0 + q))*256;
    #pragma unroll
    for (int jj = 0; jj < 8; ++jj){
      int c = sub*8 + jj*32;
      float4 v0 = *(const float4*)(rowp + c);
      float4 v1 = *(const float4*)(rowp + c + 4);
      short8 o;
      o[0] = (short)f2bf(v0.x); o[1] = (short)f2bf(v0.y);
      o[2] = (short)f2bf(v0.z); o[3] = (short)f2bf(v0.w);
      o[4] = (short)f2bf(v1.x); o[5] = (short)f2bf(v1.y);
      o[6] = (short)f2bf(v1.z); o[7] = (short)f2bf(v1.w);
      *(short8*)(dst + c) = o;
    }
  }
}

// ---------------- launch ----------------
extern "C" void kernel_launch(void* const* d_in, const int* in_sizes, int n_in,
                              void* d_out, int out_size, void* d_ws, size_t ws_size,
                              hipStream_t stream){
  const float* x      = (const float*)d_in[0];
  const float* gamma  = (const float*)d_in[1];
  const float* beta   = (const float*)d_in[2];
  const float* qkv_w  = (const float*)d_in[3];
  const float* qkv_b  = (const float*)d_in[4];
  const float* proj_w = (const float*)d_in[5];
  const float* proj_b = (const float*)d_in[6];
  float* out = (float*)d_out;
  char* ws = (char*)d_ws;

  float2* partial        = (float2*)(ws + 0);        // 2048 B
  float2* stats          = (float2*)(ws + 2048);     // 32 B
  float*  bias_qk        = (float*)(ws + 4096);      // 2048 B
  unsigned short* Wqk    = (unsigned short*)(ws + 8192);      // 512x256 bf16
  unsigned short* Wv     = (unsigned short*)(ws + 270336);    // 256x256
  unsigned short* Wp     = (unsigned short*)(ws + 401408);    // 256x256
  unsigned short* xnt    = (unsigned short*)(ws + 532480);    // 4x4096x256 bf16 (8.4 MB)
  unsigned short* qkbuf  = (unsigned short*)(ws + 8921088);   // 4x4096x512 bf16 (16.8 MB)
  unsigned short* vbuf   = (unsigned short*)(ws + 25698304);  // 4x256x4096 bf16 (8.4 MB)
  unsigned short* ho     = xnt;  // xnt dead after QKV gemms -> reuse for attention output

  reduce_partial_k<<<dim3(64,4), 256, 0, stream>>>(x, partial);
  reduce_final_k<<<1, 256, 0, stream>>>(partial, stats);
  convert_w_k<<<1024, 256, 0, stream>>>(qkv_w, qkv_b, proj_w, Wqk, Wv, Wp, bias_qk);
  norm_transpose_k<<<dim3(64,4,4), 256, 0, stream>>>(x, gamma, beta, stats, xnt);
  // qk[b][n][o] = xn_t[b][n][:] . Wqk[o][:]   (M=4096, N=512)
  gemm_nt_k<<<dim3(64,8,4), 256, 0, stream>>>(xnt, Wqk, 256, 256, 4096L*256, 0,
      nullptr, bias_qk, nullptr, 0, nullptr, qkbuf, 512, 4096L*512);
  // v[b][o][n] = Wv[o][:] . xn_t[b][n][:]     (M=256, N=4096)
  gemm_nt_k<<<dim3(4,64,4), 256, 0, stream>>>(Wv, xnt, 256, 256, 0, 4096L*256,
      qkv_b + 512, nullptr, nullptr, 0, nullptr, vbuf, 4096, 256L*4096);
  attn_k<<<dim3(64,4), 256, 0, stream>>>(qkbuf, vbuf, ho);
  // out[b][o][n] = Wp[o][:] . ho[b][n][:] + proj_b[o] + x[b][o][n]
  gemm_nt_k<<<dim3(4,64,4), 256, 0, stream>>>(Wp, ho, 256, 256, 0, 4096L*256,
      proj_b, nullptr, x, 1048576L, out, nullptr, 4096, 1048576L);
}